// Round 6
// baseline (224.028 us; speedup 1.0000x reference)
//
#include <hip/hip_runtime.h>

#define N_NODES 40000
#define N_EDGES 640000
#define D 128                 // D_IN == D_OUT == 128
#define NB 157                // ceil(N_NODES / 256) scan blocks
#define GEMM_ROWS 32          // rows per gemm block
#define GEMM_BLOCKS (N_NODES / GEMM_ROWS)    // 1250
#define DEG_BLOCKS ((N_EDGES + 255) / 256)   // 2500

// ---------------------------------------------------------------------------
// Workspace layout (16B-aligned):
//   y      : N_NODES*D f32    (x @ W)
//   deg    : N_NODES int      (in-degree; later consumed as bucket cursor)
//   invdeg : N_NODES f32
//   offs   : N_NODES+1 int    (CSR row offsets by dst)
//   bsum   : NB int           (per-block degree sums for scan)
//   pairs  : N_EDGES int2     (.x = src, .y = bits(ew)), grouped by dst
// ---------------------------------------------------------------------------

// K1 (fused): blocks [0, GEMM_BLOCKS) compute y = x@W (LDS-free, VALU-bound);
// blocks [GEMM_BLOCKS, +DEG_BLOCKS) do deg[dst[e]]++ (latency/atomic-bound).
// Independent work, fused for overlap. No LDS so degree occupancy is full.
__global__ __launch_bounds__(256) void gemm_degree_kernel(const float* __restrict__ x,
                                                          const float* __restrict__ W,
                                                          float* __restrict__ y,
                                                          const int* __restrict__ dst,
                                                          int* __restrict__ deg) {
    const int tid = threadIdx.x;
    if (blockIdx.x >= GEMM_BLOCKS) {
        // ---- degree part ----
        int e = (blockIdx.x - GEMM_BLOCKS) * 256 + tid;
        if (e < N_EDGES) atomicAdd(&deg[dst[e]], 1);
        return;
    }
    // ---- gemm part: 32 rows x 128 cols per block; thread = 4 rows x 4 cols
    const int lane = tid & 31;                    // cols [lane*4, lane*4+4)
    const int rp   = tid >> 5;                    // rows 4rp..4rp+3
    const int r0   = blockIdx.x * GEMM_ROWS + rp * 4;

    const float4* W4 = reinterpret_cast<const float4*>(W);   // [k][c/4], L2-hot
    const float4* xr0 = reinterpret_cast<const float4*>(x) + (r0 + 0) * (D / 4);
    const float4* xr1 = reinterpret_cast<const float4*>(x) + (r0 + 1) * (D / 4);
    const float4* xr2 = reinterpret_cast<const float4*>(x) + (r0 + 2) * (D / 4);
    const float4* xr3 = reinterpret_cast<const float4*>(x) + (r0 + 3) * (D / 4);

    float4 a0 = {0.f,0.f,0.f,0.f}, a1 = a0, a2 = a0, a3 = a0;
#pragma unroll 4
    for (int kb = 0; kb < D / 4; ++kb) {          // 4 k's per iteration
        float4 xv0 = xr0[kb], xv1 = xr1[kb], xv2 = xr2[kb], xv3 = xr3[kb];
        float4 w0 = W4[(kb * 4 + 0) * (D / 4) + lane];
        float4 w1 = W4[(kb * 4 + 1) * (D / 4) + lane];
        float4 w2 = W4[(kb * 4 + 2) * (D / 4) + lane];
        float4 w3 = W4[(kb * 4 + 3) * (D / 4) + lane];
#define FMA4(A, XV)                                                       \
        A.x += XV.x*w0.x + XV.y*w1.x; A.x += XV.z*w2.x + XV.w*w3.x;       \
        A.y += XV.x*w0.y + XV.y*w1.y; A.y += XV.z*w2.y + XV.w*w3.y;       \
        A.z += XV.x*w0.z + XV.y*w1.z; A.z += XV.z*w2.z + XV.w*w3.z;       \
        A.w += XV.x*w0.w + XV.y*w1.w; A.w += XV.z*w2.w + XV.w*w3.w;
        FMA4(a0, xv0) FMA4(a1, xv1) FMA4(a2, xv2) FMA4(a3, xv3)
#undef FMA4
    }
    float4* y4 = reinterpret_cast<float4*>(y);
    y4[(r0 + 0) * (D / 4) + lane] = a0;
    y4[(r0 + 1) * (D / 4) + lane] = a1;
    y4[(r0 + 2) * (D / 4) + lane] = a2;
    y4[(r0 + 3) * (D / 4) + lane] = a3;
}

// K2a: per-block (256-node) sum of deg -> bsum[block]
__global__ __launch_bounds__(256) void reduce_kernel(const int* __restrict__ deg,
                                                     int* __restrict__ bsum) {
    __shared__ int s[256];
    int t = threadIdx.x;
    int idx = blockIdx.x * 256 + t;
    s[t] = (idx < N_NODES) ? deg[idx] : 0;
    __syncthreads();
#pragma unroll
    for (int off = 128; off > 0; off >>= 1) {
        if (t < off) s[t] += s[t + off];
        __syncthreads();
    }
    if (t == 0) bsum[blockIdx.x] = s[0];
}

// K2b: offs[idx] = (sum of bsum[0..blk)) + excl_scan_within_block(deg); invdeg.
__global__ __launch_bounds__(256) void offs_kernel(const int* __restrict__ deg,
                                                   const int* __restrict__ bsum,
                                                   int* __restrict__ offs,
                                                   float* __restrict__ invdeg) {
    __shared__ int s[256];
    __shared__ int base_s;
    int t = threadIdx.x;

    int v = (t < blockIdx.x && t < NB) ? bsum[t] : 0;
    s[t] = v;
    __syncthreads();
#pragma unroll
    for (int off = 128; off > 0; off >>= 1) {
        if (t < off) s[t] += s[t + off];
        __syncthreads();
    }
    if (t == 0) base_s = s[0];
    __syncthreads();
    int base = base_s;
    __syncthreads();

    int idx = blockIdx.x * 256 + t;
    int d = (idx < N_NODES) ? deg[idx] : 0;
    s[t] = d;
    __syncthreads();
#pragma unroll
    for (int off = 1; off < 256; off <<= 1) {
        int u = (t >= off) ? s[t - off] : 0;
        __syncthreads();
        s[t] += u;
        __syncthreads();
    }
    int excl = s[t] - d + base;
    if (idx < N_NODES) {
        offs[idx] = excl;
        invdeg[idx] = (d > 0) ? (1.0f / (float)d) : 0.0f;
        if (idx == N_NODES - 1) offs[N_NODES] = excl + d;   // == N_EDGES
    }
}

// K3: bucket edges by dst. deg doubles as the fill cursor (atomicSub);
// single nontemporal 8B store per edge (avoid dirty-line write amplification
// across the 8 non-coherent L2s).
__global__ __launch_bounds__(256) void bucket_kernel(const int* __restrict__ src,
                                                     const int* __restrict__ dst,
                                                     const float* __restrict__ ew,
                                                     const int* __restrict__ offs,
                                                     int* __restrict__ deg,
                                                     long long* __restrict__ pairs) {
    int e = blockIdx.x * 256 + threadIdx.x;
    if (e >= N_EDGES) return;
    int d = dst[e];
    int c = atomicSub(&deg[d], 1);                 // old value: deg..1
    int pos = offs[d] + c - 1;
    unsigned long long packed = (unsigned long long)(unsigned int)src[e]
                              | ((unsigned long long)(unsigned int)__float_as_uint(ew[e]) << 32);
    __builtin_nontemporal_store((long long)packed, &pairs[pos]);
}

// K4: per-node gather-reduce. 32 lanes per node, one float4 per lane.
// 4-deep unroll with 4 independent accumulators -> 4 outstanding y loads.
// out[v][:] = invdeg[v] * sum_e ew_e * y[src_e][:] + b[:]
__global__ __launch_bounds__(256) void gather_kernel(const int* __restrict__ offs,
                                                     const int2* __restrict__ pairs,
                                                     const float* __restrict__ invdeg,
                                                     const float* __restrict__ y,
                                                     const float* __restrict__ b,
                                                     float* __restrict__ out) {
    int gid = blockIdx.x * 256 + threadIdx.x;
    int v    = gid >> 5;
    int part = gid & 31;
    if (v >= N_NODES) return;
    int beg = offs[v];
    int end = offs[v + 1];
    const float4* y4 = reinterpret_cast<const float4*>(y);
    float4 acc0 = {0.f,0.f,0.f,0.f}, acc1 = acc0, acc2 = acc0, acc3 = acc0;
    for (int base = beg; base < end; base += 32) {
        int n = end - base; if (n > 32) n = 32;
        int2 pe = make_int2(0, 0);
        if (part < n) pe = pairs[base + part];
        int j = 0;
        for (; j + 4 <= n; j += 4) {
            int   s0 = __shfl(pe.x, j + 0, 32), s1 = __shfl(pe.x, j + 1, 32);
            int   s2 = __shfl(pe.x, j + 2, 32), s3 = __shfl(pe.x, j + 3, 32);
            float w0 = __int_as_float(__shfl(pe.y, j + 0, 32));
            float w1 = __int_as_float(__shfl(pe.y, j + 1, 32));
            float w2 = __int_as_float(__shfl(pe.y, j + 2, 32));
            float w3 = __int_as_float(__shfl(pe.y, j + 3, 32));
            float4 t0 = y4[s0 * (D / 4) + part];
            float4 t1 = y4[s1 * (D / 4) + part];
            float4 t2 = y4[s2 * (D / 4) + part];
            float4 t3 = y4[s3 * (D / 4) + part];
            acc0.x += w0*t0.x; acc0.y += w0*t0.y; acc0.z += w0*t0.z; acc0.w += w0*t0.w;
            acc1.x += w1*t1.x; acc1.y += w1*t1.y; acc1.z += w1*t1.z; acc1.w += w1*t1.w;
            acc2.x += w2*t2.x; acc2.y += w2*t2.y; acc2.z += w2*t2.z; acc2.w += w2*t2.w;
            acc3.x += w3*t3.x; acc3.y += w3*t3.y; acc3.z += w3*t3.z; acc3.w += w3*t3.w;
        }
        for (; j < n; ++j) {
            int   s = __shfl(pe.x, j, 32);
            float w = __int_as_float(__shfl(pe.y, j, 32));
            float4 t = y4[s * (D / 4) + part];
            acc0.x += w*t.x; acc0.y += w*t.y; acc0.z += w*t.z; acc0.w += w*t.w;
        }
    }
    float idv = invdeg[v];
    float4 bv = reinterpret_cast<const float4*>(b)[part];
    float4 r;
    r.x = (acc0.x + acc1.x + acc2.x + acc3.x) * idv + bv.x;
    r.y = (acc0.y + acc1.y + acc2.y + acc3.y) * idv + bv.y;
    r.z = (acc0.z + acc1.z + acc2.z + acc3.z) * idv + bv.z;
    r.w = (acc0.w + acc1.w + acc2.w + acc3.w) * idv + bv.w;
    reinterpret_cast<float4*>(out)[v * (D / 4) + part] = r;
}

// ---------------------------------------------------------------------------
extern "C" void kernel_launch(void* const* d_in, const int* in_sizes, int n_in,
                              void* d_out, int out_size, void* d_ws, size_t ws_size,
                              hipStream_t stream) {
    const float* x   = (const float*)d_in[0];
    const int*   src = (const int*)d_in[1];
    const int*   dst = (const int*)d_in[2];
    const float* ew  = (const float*)d_in[3];
    const float* W   = (const float*)d_in[4];
    const float* b   = (const float*)d_in[5];
    float* out = (float*)d_out;

    char* ws = (char*)d_ws;
    float* y      = (float*)ws;                       ws += (size_t)N_NODES * D * 4;
    int*   deg    = (int*)ws;                         ws += (size_t)N_NODES * 4;
    float* invdeg = (float*)ws;                       ws += (size_t)N_NODES * 4;
    int*   offs   = (int*)ws;                         ws += (size_t)(N_NODES + 16) * 4;
    int*   bsum   = (int*)ws;                         ws += (size_t)((NB + 19) & ~3) * 4;
    long long* pairs = (long long*)ws;

    // zero the degree counters (graph-capturable async memset)
    hipMemsetAsync(deg, 0, (size_t)N_NODES * 4, stream);

    gemm_degree_kernel<<<GEMM_BLOCKS + DEG_BLOCKS, 256, 0, stream>>>(x, W, y, dst, deg);
    reduce_kernel<<<NB, 256, 0, stream>>>(deg, bsum);
    offs_kernel<<<NB, 256, 0, stream>>>(deg, bsum, offs, invdeg);
    bucket_kernel<<<DEG_BLOCKS, 256, 0, stream>>>(src, dst, ew, offs, deg, pairs);
    {
        long long total = (long long)N_NODES * 32;
        gather_kernel<<<(int)((total + 255) / 256), 256, 0, stream>>>(
            offs, (const int2*)pairs, invdeg, y, b, out);
    }
}

// Round 7
// 219.160 us; speedup vs baseline: 1.0222x; 1.0222x over previous
//
#include <hip/hip_runtime.h>

#define N_NODES 40000
#define N_EDGES 640000
#define D 128                 // D_IN == D_OUT == 128
#define NB 157                // ceil(N_NODES / 256) scan blocks
#define GEMM_ROWS 32          // rows per gemm block (40000/32 = 1250 exact)
#define EDGE_BLOCKS ((N_EDGES + 255) / 256)   // 2500

typedef float f32x4 __attribute__((ext_vector_type(4)));

// ---------------------------------------------------------------------------
// Workspace layout (16B-aligned):
//   y      : N_NODES*D f32    (x @ W)
//   deg    : N_NODES int      (in-degree; later consumed as bucket cursor)
//   invdeg : N_NODES f32
//   offs   : N_NODES+1 int    (CSR row offsets by dst)
//   bsum   : NB int           (per-block degree sums for scan)
//   pairs  : N_EDGES i64      (lo32 = src, hi32 = bits(ew)), grouped by dst
// ---------------------------------------------------------------------------

// K1: deg[dst[e]]++  (640k int atomics over 160 KB -> L2-resident)
__global__ __launch_bounds__(256) void degree_kernel(const int* __restrict__ dst,
                                                     int* __restrict__ deg) {
    int e = blockIdx.x * 256 + threadIdx.x;
    if (e < N_EDGES) atomicAdd(&deg[dst[e]], 1);
}

// K2a: per-block (256-node) sum of deg -> bsum[block]
__global__ __launch_bounds__(256) void reduce_kernel(const int* __restrict__ deg,
                                                     int* __restrict__ bsum) {
    __shared__ int s[256];
    int t = threadIdx.x;
    int idx = blockIdx.x * 256 + t;
    s[t] = (idx < N_NODES) ? deg[idx] : 0;
    __syncthreads();
#pragma unroll
    for (int off = 128; off > 0; off >>= 1) {
        if (t < off) s[t] += s[t + off];
        __syncthreads();
    }
    if (t == 0) bsum[blockIdx.x] = s[0];
}

// K2b: offs[idx] = (sum of bsum[0..blk)) + excl_scan_within_block(deg); invdeg.
__global__ __launch_bounds__(256) void offs_kernel(const int* __restrict__ deg,
                                                   const int* __restrict__ bsum,
                                                   int* __restrict__ offs,
                                                   float* __restrict__ invdeg) {
    __shared__ int s[256];
    __shared__ int base_s;
    int t = threadIdx.x;

    int v = (t < blockIdx.x && t < NB) ? bsum[t] : 0;
    s[t] = v;
    __syncthreads();
#pragma unroll
    for (int off = 128; off > 0; off >>= 1) {
        if (t < off) s[t] += s[t + off];
        __syncthreads();
    }
    if (t == 0) base_s = s[0];
    __syncthreads();
    int base = base_s;
    __syncthreads();

    int idx = blockIdx.x * 256 + t;
    int d = (idx < N_NODES) ? deg[idx] : 0;
    s[t] = d;
    __syncthreads();
#pragma unroll
    for (int off = 1; off < 256; off <<= 1) {
        int u = (t >= off) ? s[t - off] : 0;
        __syncthreads();
        s[t] += u;
        __syncthreads();
    }
    int excl = s[t] - d + base;
    if (idx < N_NODES) {
        offs[idx] = excl;
        invdeg[idx] = (d > 0) ? (1.0f / (float)d) : 0.0f;
        if (idx == N_NODES - 1) offs[N_NODES] = excl + d;   // == N_EDGES
    }
}

// K3: bucket edges by dst. deg doubles as the fill cursor (atomicSub);
// single nontemporal 8B store per edge (avoid dirty-line write amplification).
__global__ __launch_bounds__(256) void bucket_kernel(const int* __restrict__ src,
                                                     const int* __restrict__ dst,
                                                     const float* __restrict__ ew,
                                                     const int* __restrict__ offs,
                                                     int* __restrict__ deg,
                                                     long long* __restrict__ pairs) {
    int e = blockIdx.x * 256 + threadIdx.x;
    if (e >= N_EDGES) return;
    int d = dst[e];
    int c = atomicSub(&deg[d], 1);                 // old value: deg..1
    int pos = offs[d] + c - 1;
    unsigned long long packed = (unsigned long long)(unsigned int)src[e]
                              | ((unsigned long long)__float_as_uint(ew[e]) << 32);
    __builtin_nontemporal_store((long long)packed, &pairs[pos]);
}

// K4: y = x @ W (fp32 vector GEMM; no fp32 MFMA on CDNA4).
// Block = 256 threads computes a 32-row x 128-col tile; W (64KB) + x tile
// (16KB) staged in LDS (REQUIRED: global-W version is latency-bound, R6).
__global__ __launch_bounds__(256) void gemm_xw_kernel(const float* __restrict__ x,
                                                      const float* __restrict__ W,
                                                      float* __restrict__ y) {
    __shared__ float Ws[D * D];             // 64 KB, [k][c] row-major
    __shared__ float xs[GEMM_ROWS * D];     // 16 KB
    const int tid = threadIdx.x;
    const int rowbase = blockIdx.x * GEMM_ROWS;

    float4* Ws4 = reinterpret_cast<float4*>(Ws);
    const float4* W4 = reinterpret_cast<const float4*>(W);
#pragma unroll
    for (int i = 0; i < 16; ++i)                  // 4096 float4 / 256 thr
        Ws4[tid + i * 256] = W4[tid + i * 256];

    float4* xs4 = reinterpret_cast<float4*>(xs);
    const float4* x4 = reinterpret_cast<const float4*>(x) + rowbase * (D / 4);
#pragma unroll
    for (int i = 0; i < GEMM_ROWS * (D / 4) / 256; ++i)   // 1024/256 = 4
        xs4[tid + i * 256] = x4[tid + i * 256];
    __syncthreads();

    const int lane = tid & 31;
    const int rp   = tid >> 5;                    // 0..7 -> rows 4rp..4rp+3
    const float* xr0 = xs + (rp * 4 + 0) * D;
    const float* xr1 = xs + (rp * 4 + 1) * D;
    const float* xr2 = xs + (rp * 4 + 2) * D;
    const float* xr3 = xs + (rp * 4 + 3) * D;

    float4 a0 = {0.f,0.f,0.f,0.f}, a1 = a0, a2 = a0, a3 = a0;
#pragma unroll 4
    for (int k = 0; k < D; ++k) {
        float4 wv = Ws4[k * (D / 4) + lane];      // ds_read_b128
        float x0 = xr0[k], x1 = xr1[k], x2 = xr2[k], x3 = xr3[k];
        a0.x += x0*wv.x; a0.y += x0*wv.y; a0.z += x0*wv.z; a0.w += x0*wv.w;
        a1.x += x1*wv.x; a1.y += x1*wv.y; a1.z += x1*wv.z; a1.w += x1*wv.w;
        a2.x += x2*wv.x; a2.y += x2*wv.y; a2.z += x2*wv.z; a2.w += x2*wv.w;
        a3.x += x3*wv.x; a3.y += x3*wv.y; a3.z += x3*wv.z; a3.w += x3*wv.w;
    }

    float4* y4 = reinterpret_cast<float4*>(y);
    int r0 = rowbase + rp * 4;
    y4[(r0 + 0) * (D / 4) + lane] = a0;
    y4[(r0 + 1) * (D / 4) + lane] = a1;
    y4[(r0 + 2) * (D / 4) + lane] = a2;
    y4[(r0 + 3) * (D / 4) + lane] = a3;
}

// K5: per-node gather-reduce. 32 lanes per node, one float4 per lane.
// 4-deep unroll -> 4 outstanding y loads. pairs read nontemporal (read-once);
// out stored nontemporal (write-once) to keep y hot in L2.
__global__ __launch_bounds__(256) void gather_kernel(const int* __restrict__ offs,
                                                     const long long* __restrict__ pairs,
                                                     const float* __restrict__ invdeg,
                                                     const float* __restrict__ y,
                                                     const float* __restrict__ b,
                                                     float* __restrict__ out) {
    int gid = blockIdx.x * 256 + threadIdx.x;
    int v    = gid >> 5;
    int part = gid & 31;
    if (v >= N_NODES) return;
    int beg = offs[v];
    int end = offs[v + 1];
    const float4* y4 = reinterpret_cast<const float4*>(y);
    float4 acc0 = {0.f,0.f,0.f,0.f}, acc1 = acc0, acc2 = acc0, acc3 = acc0;
    for (int base = beg; base < end; base += 32) {
        int n = end - base; if (n > 32) n = 32;
        long long pv = 0;
        if (part < n) pv = __builtin_nontemporal_load(&pairs[base + part]);
        int pex = (int)(unsigned int)((unsigned long long)pv & 0xffffffffull);
        int pey = (int)(unsigned int)((unsigned long long)pv >> 32);
        int j = 0;
        for (; j + 4 <= n; j += 4) {
            int   s0 = __shfl(pex, j + 0, 32), s1 = __shfl(pex, j + 1, 32);
            int   s2 = __shfl(pex, j + 2, 32), s3 = __shfl(pex, j + 3, 32);
            float w0 = __int_as_float(__shfl(pey, j + 0, 32));
            float w1 = __int_as_float(__shfl(pey, j + 1, 32));
            float w2 = __int_as_float(__shfl(pey, j + 2, 32));
            float w3 = __int_as_float(__shfl(pey, j + 3, 32));
            float4 t0 = y4[s0 * (D / 4) + part];
            float4 t1 = y4[s1 * (D / 4) + part];
            float4 t2 = y4[s2 * (D / 4) + part];
            float4 t3 = y4[s3 * (D / 4) + part];
            acc0.x += w0*t0.x; acc0.y += w0*t0.y; acc0.z += w0*t0.z; acc0.w += w0*t0.w;
            acc1.x += w1*t1.x; acc1.y += w1*t1.y; acc1.z += w1*t1.z; acc1.w += w1*t1.w;
            acc2.x += w2*t2.x; acc2.y += w2*t2.y; acc2.z += w2*t2.z; acc2.w += w2*t2.w;
            acc3.x += w3*t3.x; acc3.y += w3*t3.y; acc3.z += w3*t3.z; acc3.w += w3*t3.w;
        }
        for (; j < n; ++j) {
            int   s = __shfl(pex, j, 32);
            float w = __int_as_float(__shfl(pey, j, 32));
            float4 t = y4[s * (D / 4) + part];
            acc0.x += w*t.x; acc0.y += w*t.y; acc0.z += w*t.z; acc0.w += w*t.w;
        }
    }
    float idv = invdeg[v];
    float4 bv = reinterpret_cast<const float4*>(b)[part];
    f32x4 r;
    r.x = (acc0.x + acc1.x + acc2.x + acc3.x) * idv + bv.x;
    r.y = (acc0.y + acc1.y + acc2.y + acc3.y) * idv + bv.y;
    r.z = (acc0.z + acc1.z + acc2.z + acc3.z) * idv + bv.z;
    r.w = (acc0.w + acc1.w + acc2.w + acc3.w) * idv + bv.w;
    __builtin_nontemporal_store(r, reinterpret_cast<f32x4*>(out) + v * (D / 4) + part);
}

// ---------------------------------------------------------------------------
extern "C" void kernel_launch(void* const* d_in, const int* in_sizes, int n_in,
                              void* d_out, int out_size, void* d_ws, size_t ws_size,
                              hipStream_t stream) {
    const float* x   = (const float*)d_in[0];
    const int*   src = (const int*)d_in[1];
    const int*   dst = (const int*)d_in[2];
    const float* ew  = (const float*)d_in[3];
    const float* W   = (const float*)d_in[4];
    const float* b   = (const float*)d_in[5];
    float* out = (float*)d_out;

    char* ws = (char*)d_ws;
    float* y      = (float*)ws;                       ws += (size_t)N_NODES * D * 4;
    int*   deg    = (int*)ws;                         ws += (size_t)N_NODES * 4;
    float* invdeg = (float*)ws;                       ws += (size_t)N_NODES * 4;
    int*   offs   = (int*)ws;                         ws += (size_t)(N_NODES + 16) * 4;
    int*   bsum   = (int*)ws;                         ws += (size_t)((NB + 19) & ~3) * 4;
    long long* pairs = (long long*)ws;

    hipMemsetAsync(deg, 0, (size_t)N_NODES * 4, stream);

    degree_kernel<<<EDGE_BLOCKS, 256, 0, stream>>>(dst, deg);
    reduce_kernel<<<NB, 256, 0, stream>>>(deg, bsum);
    offs_kernel<<<NB, 256, 0, stream>>>(deg, bsum, offs, invdeg);
    bucket_kernel<<<EDGE_BLOCKS, 256, 0, stream>>>(src, dst, ew, offs, deg, pairs);
    gemm_xw_kernel<<<N_NODES / GEMM_ROWS, 256, 0, stream>>>(x, W, y);
    {
        long long total = (long long)N_NODES * 32;
        gather_kernel<<<(int)((total + 255) / 256), 256, 0, stream>>>(
            offs, pairs, invdeg, y, b, out);
    }
}